// Round 4
// baseline (136.032 us; speedup 1.0000x reference)
//
#include <hip/hip_runtime.h>

// FP16 bit-vector -> FP32 bit-vector converter, wave-cooperative layout.
// Input:  N x 16 float32 (0.0/1.0), MSB-first fp16 bits (s, e[5], m[10])
// Output: N x 32 float32, MSB-first fp32 bits (s, exp[8], mant[23])
//
// Each wave processes 32 rows per iteration (2x unrolled):
//   load : lane l reads uint4 #(base+l), #(base+64+l)   -> contiguous 1 KiB/instr
//   bits : 4x __ballot per 16-row group collect all fp16 patterns
//   store: 4 contiguous 1 KiB/instr float4 stores, nontemporal
//
// NOTE: __builtin_nontemporal_* requires native clang vectors, not
// HIP_vector_type structs -> use ext_vector_type typedefs.

typedef unsigned long long ull;
typedef unsigned int u32x4 __attribute__((ext_vector_type(4)));
typedef float         f32x4 __attribute__((ext_vector_type(4)));

__device__ __forceinline__ unsigned h_from_ballots(ull b0, ull b1, ull b2, ull b3,
                                                   int base) {
    unsigned t0 = (unsigned)(b0 >> base);
    unsigned t1 = (unsigned)(b1 >> base);
    unsigned t2 = (unsigned)(b2 >> base);
    unsigned t3 = (unsigned)(b3 >> base);
    return ((t0 & 1u) << 15) | ((t1 & 1u) << 14) | ((t2 & 1u) << 13) | ((t3 & 1u) << 12) |
           (((t0 >> 1) & 1u) << 11) | (((t1 >> 1) & 1u) << 10) | (((t2 >> 1) & 1u) << 9)  | (((t3 >> 1) & 1u) << 8) |
           (((t0 >> 2) & 1u) << 7)  | (((t1 >> 2) & 1u) << 6)  | (((t2 >> 2) & 1u) << 5)  | (((t3 >> 2) & 1u) << 4) |
           (((t0 >> 3) & 1u) << 3)  | (((t1 >> 3) & 1u) << 2)  | (((t2 >> 3) & 1u) << 1)  | ((t3 >> 3) & 1u);
}

__device__ __forceinline__ unsigned fp16_bits_to_fp32_bits(unsigned h) {
    unsigned s = h >> 15;
    unsigned e = (h >> 10) & 31u;
    unsigned m = h & 1023u;
    int k = (m == 0u) ? 10 : (__clz((int)m) - 22);        // leading zeros in 10-bit m
    unsigned sub_mant = (m << (14 + k)) & 0x7FFFFFu;      // leading 1 shifted out
    unsigned sub_exp  = m ? (112u - (unsigned)k) : 0u;
    unsigned exp32 = (e == 0u) ? sub_exp : ((e == 31u) ? 255u : e + 112u);
    unsigned mant  = (e == 0u) ? sub_mant : (m << 13);    // e==31: inf->0, nan payload
    return (s << 31) | (exp32 << 23) | mant;
}

__device__ __forceinline__ f32x4 nib_to_f4(unsigned nib) {
    f32x4 v;
    v.x = (float)((nib >> 3) & 1u);
    v.y = (float)((nib >> 2) & 1u);
    v.z = (float)((nib >> 1) & 1u);
    v.w = (float)(nib & 1u);
    return v;
}

__global__ __launch_bounds__(256) void fp16_to_fp32_bits_kernel(
    const u32x4* __restrict__ in,    // 4*N uint4
    f32x4* __restrict__ out,         // 8*N float4
    unsigned total4)                 // 4*N
{
    int l = threadIdx.x & 63;
    // Each thread handles uint4 indices g0 and g0+64 (wave-contiguous pair).
    unsigned wave_base = (blockIdx.x * 256u + (threadIdx.x & ~63u)) * 2u;
    unsigned g0 = wave_base + (unsigned)l;
    unsigned g1 = g0 + 64u;

    u32x4 zero = {0u, 0u, 0u, 0u};
    u32x4 a0 = (g0 < total4) ? __builtin_nontemporal_load(&in[g0]) : zero;
    u32x4 a1 = (g1 < total4) ? __builtin_nontemporal_load(&in[g1]) : zero;

    int rA = l >> 3;   // row within 16-row group; second row is rA+8
    int j  = l & 7;    // float4 chunk within row
    int sh = 28 - 4 * j;

    // ---- group 0: rows wave_base/4 .. +15 ----
    {
        ull b0 = __ballot(a0.x != 0u);
        ull b1 = __ballot(a0.y != 0u);
        ull b2 = __ballot(a0.z != 0u);
        ull b3 = __ballot(a0.w != 0u);
        unsigned rsA = fp16_bits_to_fp32_bits(h_from_ballots(b0, b1, b2, b3, 4 * rA));
        unsigned rsB = fp16_bits_to_fp32_bits(h_from_ballots(b0, b1, b2, b3, 4 * rA + 32));
        unsigned ob = 2u * wave_base;
        if (g0 < total4) {
            __builtin_nontemporal_store(nib_to_f4((rsA >> sh) & 0xFu), &out[ob + (unsigned)l]);
            __builtin_nontemporal_store(nib_to_f4((rsB >> sh) & 0xFu), &out[ob + 64u + (unsigned)l]);
        }
    }
    // ---- group 1: next 16 rows ----
    {
        ull b0 = __ballot(a1.x != 0u);
        ull b1 = __ballot(a1.y != 0u);
        ull b2 = __ballot(a1.z != 0u);
        ull b3 = __ballot(a1.w != 0u);
        unsigned rsA = fp16_bits_to_fp32_bits(h_from_ballots(b0, b1, b2, b3, 4 * rA));
        unsigned rsB = fp16_bits_to_fp32_bits(h_from_ballots(b0, b1, b2, b3, 4 * rA + 32));
        unsigned ob = 2u * wave_base + 128u;
        if (g1 < total4) {
            __builtin_nontemporal_store(nib_to_f4((rsA >> sh) & 0xFu), &out[ob + (unsigned)l]);
            __builtin_nontemporal_store(nib_to_f4((rsB >> sh) & 0xFu), &out[ob + 64u + (unsigned)l]);
        }
    }
}

extern "C" void kernel_launch(void* const* d_in, const int* in_sizes, int n_in,
                              void* d_out, int out_size, void* d_ws, size_t ws_size,
                              hipStream_t stream) {
    (void)d_ws; (void)ws_size; (void)n_in; (void)out_size;
    unsigned n = (unsigned)(in_sizes[0] / 16);  // rows
    unsigned total4 = n * 4u;                   // uint4 elements in input
    const u32x4* in = (const u32x4*)d_in[0];
    f32x4* out = (f32x4*)d_out;
    // each block of 256 threads covers 512 uint4s
    unsigned blocks = (total4 + 511u) / 512u;
    fp16_to_fp32_bits_kernel<<<blocks, 256, 0, stream>>>(in, out, total4);
}